// Round 13
// baseline (254.955 us; speedup 1.0000x reference)
//
#include <hip/hip_runtime.h>
#include <hip/hip_bf16.h>
#include <stdint.h>

#define BATCH 4096
#define KGRP  8
#define BLK   1024
#define TOTAL 8192

typedef __attribute__((ext_vector_type(8))) short short8;
typedef __attribute__((ext_vector_type(4))) float f32x4;

#define AS1 __attribute__((address_space(1)))
#define AS3 __attribute__((address_space(3)))

// ---------- helpers ----------

__device__ __forceinline__ unsigned short f2bf(float f) {
    union { float f; uint32_t u; } c; c.f = f;
    uint32_t u = c.u;
    u += 0x7fffu + ((u >> 16) & 1u);   // round-to-nearest-even
    return (unsigned short)(u >> 16);
}

__device__ __forceinline__ float fast_tanh(float x) {
    float e = __expf(2.0f * x);
    return 1.0f - 2.0f / (e + 1.0f);
}

__device__ __forceinline__ void gload16(const unsigned short* src, char* dst) {
    __builtin_amdgcn_global_load_lds((const AS1 uint32_t*)src, (AS3 uint32_t*)dst, 16, 0, 0);
}

template<int N> __device__ __forceinline__ void waitvm() {
    if constexpr (N == 0)      asm volatile("s_waitcnt vmcnt(0)" ::: "memory");
    else if constexpr (N == 4) asm volatile("s_waitcnt vmcnt(4)" ::: "memory");
    else if constexpr (N == 5) asm volatile("s_waitcnt vmcnt(5)" ::: "memory");
}

// ---------- prep: W f32 -> bf16 (48 MB traffic, ~8 us; the ONLY prep left) ----------

__global__ void k_wcast(const float4* __restrict__ W, ushort4* __restrict__ Wb) {
    const int n4 = KGRP * BLK * BLK / 4;
    for (int i = blockIdx.x * 256 + threadIdx.x; i < n4; i += 1024 * 256) {
        float4 f = W[i];
        ushort4 o;
        o.x = f2bf(f.x); o.y = f2bf(f.y); o.z = f2bf(f.z); o.w = f2bf(f.w);
        Wb[i] = o;
    }
}

// ---------- fused GEMM: r7 skeleton, 64x512 block, tanh fused at 2x redundancy ----------
// Block = 64 rows x 512 cols of group g; 8 waves, each 64x64 (distinct w = col panel).
// A[64][32] bf16 (4 KB) + B[512][32] bf16 (32 KB) per buffer; dbuf stride 36864;
// LDS total 73728 -> 2 blocks/CU (launch_bounds(512,4), VGPR<=128).
// A: v -> float4 reg (3-tile-deep rotating slots, compiler-tracked loads) ->
//    tanh -> bf16 -> swizzled ds_write (4 B-elems/thread/tile). tanh redundancy
//    = 2x (64-row panel shared by the 2 ntile blocks) -- r12's 4x was the fail.
// B: r7-verified pre-swizzled-source gload_lds DMA, 4 per wave per tile.
// Swizzle both sides (r4-r9 verified, conflicts==0): phys16Bslot = log ^ ((row>>1)&3).
//
// vmcnt (conservative region counting; sched_barrier(0) at boundaries pins tiles):
//   steady tile kt issues [ph0: v(kt+4) x1][ph1: B-DMA(kt+2) x4]; boundary guards
//   B(kt+1) -> newer = 5 -> vmcnt(5). Tails: kt=28,29 no v -> vmcnt(4);
//   kt=30 nothing -> vmcnt(0); kt=31 no stage/no boundary. (r3 lesson: exact counts.)
// Hazards: A-write(kt+1)->buf^1 whose readers (kt-1) passed boundary(kt-1); A-write
// published by lgkmcnt(0) before boundary; B-DMA(kt+2)->cur's B region consumed at
// ph0(kt), mid-barrier separated (r7-verified pattern).

template<int SLOT, bool WRA, bool RV, bool SB, int W>
__device__ __forceinline__ void tile_f(int kt, char* ldsp,
                                       uint32_t aRd, uint32_t bRd, uint32_t aWr,
                                       const float* vsrc, const unsigned short* BsrcT,
                                       uint32_t sdstB, float4 (&vs)[3],
                                       f32x4 (*acc)[4]) {
    const uint32_t cur = (uint32_t)(kt & 1) * 36864u;
    const uint32_t oth = cur ^ 36864u;
    const char* Lb = ldsp + cur;

    short8 bfr[4], am[2];

    // ---- ph0: read B all + A m0,m1; write A(kt+1) from slot; reload slot v(kt+4) ----
#pragma unroll
    for (int n = 0; n < 4; ++n)
        bfr[n] = *(const short8*)(Lb + bRd + n * 1024);
#pragma unroll
    for (int i = 0; i < 2; ++i)
        am[i] = *(const short8*)(Lb + aRd + i * 1024);
    if constexpr (WRA) {
        const float4 vc = vs[SLOT];
        ushort4 p;
        p.x = f2bf(fast_tanh(vc.x)); p.y = f2bf(fast_tanh(vc.y));
        p.z = f2bf(fast_tanh(vc.z)); p.w = f2bf(fast_tanh(vc.w));
        *(ushort4*)(ldsp + oth + aWr) = p;
    }
    if constexpr (RV)
        vs[SLOT] = *(const float4*)(vsrc + (kt + 4) * 32);
    __builtin_amdgcn_s_setprio(1);
#pragma unroll
    for (int i = 0; i < 2; ++i)
#pragma unroll
        for (int n = 0; n < 4; ++n)
            acc[i][n] = __builtin_amdgcn_mfma_f32_16x16x32_bf16(am[i], bfr[n], acc[i][n], 0, 0, 0);
    __builtin_amdgcn_s_setprio(0);
    __builtin_amdgcn_s_barrier();

    // ---- ph1: read A m2,m3; DMA B(kt+2) into cur's B region ----
#pragma unroll
    for (int i = 0; i < 2; ++i)
        am[i] = *(const short8*)(Lb + aRd + (2 + i) * 1024);
    if constexpr (SB) {
#pragma unroll
        for (int c = 0; c < 4; ++c)
            gload16(BsrcT + (size_t)(c * 128) * BLK + (size_t)(kt + 2) * 32,
                    ldsp + cur + 4096u + (uint32_t)c * 8192u + sdstB);
    }
    __builtin_amdgcn_s_setprio(1);
#pragma unroll
    for (int i = 0; i < 2; ++i)
#pragma unroll
        for (int n = 0; n < 4; ++n)
            acc[2 + i][n] = __builtin_amdgcn_mfma_f32_16x16x32_bf16(am[i], bfr[n], acc[2 + i][n], 0, 0, 0);
    __builtin_amdgcn_s_setprio(0);
    if constexpr (W >= 0) {
        asm volatile("s_waitcnt lgkmcnt(0)" ::: "memory");   // publish A ds_write
        waitvm<W>();
        __builtin_amdgcn_s_barrier();
        __builtin_amdgcn_sched_barrier(0);
    }
}

__global__ __launch_bounds__(512, 4)
void k_main(const float* __restrict__ v, const unsigned short* __restrict__ Wb,
            const float* __restrict__ x, const float* __restrict__ bias,
            float* __restrict__ out) {
    __shared__ __attribute__((aligned(1024))) char lds[73728];   // 2 x 36864; bounce reuses buf0
    char* ldsp = lds;

    // XCD affinity: bid&7 == XCD; Wb[g] (2MB) L2-resident. ntile pair adjacent -> v L2-shared.
    const int bid   = blockIdx.x;              // 0..1023
    const int g     = bid & 7;
    const int slot  = bid >> 3;                // 0..127
    const int mtile = slot >> 1;               // 0..63  (64-row panels)
    const int ntile = slot & 1;                // 0..1   (512-col halves)
    const int gout  = (g + 1) & 7;

    const int tid  = threadIdx.x;
    const int lane = tid & 63;
    const int w    = tid >> 6;                 // 0..7 == wave's 64-col panel

    // A ds_read: row = mf*16 + (lane&15), log slot = lane>>4; phys ^= (row>>1)&3
    const uint32_t kc  = ((uint32_t)((lane >> 4) ^ ((lane >> 1) & 3))) << 4;
    const uint32_t aRd = (uint32_t)(lane & 15) * 64u + kc;                       // A @0
    const uint32_t bRd = 4096u + (uint32_t)(w * 64 + (lane & 15)) * 64u + kc;    // B @4K

    // A ds_write: thread t -> row t>>3, bytes (t&7)*8; phys slot = ((t>>1)&3)^((t>>4)&3)
    const uint32_t aWr = (uint32_t)(tid >> 3) * 64u +
                         (((uint32_t)(((tid >> 1) & 3) ^ ((tid >> 4) & 3))) << 4) +
                         (uint32_t)(tid & 1) * 8u;
    // v source: row mtile*64 + (t>>3), elems (t&7)*4 (+kt*32 per tile)
    const float* vsrc = v + (size_t)(mtile * 64 + (tid >> 3)) * TOTAL
                          + (size_t)g * BLK + (tid & 7) * 4;

    // B staging source pre-swizzle (r7-verified): row = c*128 + (t>>2)
    const int sColB = ((tid & 3) ^ ((tid >> 3) & 3)) << 3;
    const unsigned short* BsrcT = Wb + (size_t)g * BLK * BLK
                                     + (size_t)(ntile * 512 + (tid >> 2)) * BLK + sColB;
    const uint32_t sdstB = (uint32_t)(w << 10);   // wave-uniform; HW adds lane*16

    f32x4 acc[4][4];
#pragma unroll
    for (int m = 0; m < 4; ++m)
#pragma unroll
        for (int n = 0; n < 4; ++n) acc[m][n] = (f32x4){0.f, 0.f, 0.f, 0.f};

    // prologue: B(0)->buf0, B(1)->buf1 (DMA); A(0) direct; slots v(1),v(2),v(3)
    float4 vs[3];
#pragma unroll
    for (int c = 0; c < 4; ++c)
        gload16(BsrcT + (size_t)(c * 128) * BLK, ldsp + 4096u + (uint32_t)c * 8192u + sdstB);
#pragma unroll
    for (int c = 0; c < 4; ++c)
        gload16(BsrcT + (size_t)(c * 128) * BLK + 32, ldsp + 36864u + 4096u + (uint32_t)c * 8192u + sdstB);
    {
        float4 v0 = *(const float4*)(vsrc);
        vs[1] = *(const float4*)(vsrc + 32);   // v(1), consumed kt=0
        vs[2] = *(const float4*)(vsrc + 64);   // v(2), consumed kt=1
        vs[0] = *(const float4*)(vsrc + 96);   // v(3), consumed kt=2
        ushort4 p;
        p.x = f2bf(fast_tanh(v0.x)); p.y = f2bf(fast_tanh(v0.y));
        p.z = f2bf(fast_tanh(v0.z)); p.w = f2bf(fast_tanh(v0.w));
        *(ushort4*)(ldsp + aWr) = p;
    }
    asm volatile("s_waitcnt lgkmcnt(0)" ::: "memory");
    waitvm<4>();                               // both B DMAs = 8 oldest; leaves v regs flying
    __builtin_amdgcn_s_barrier();
    __builtin_amdgcn_sched_barrier(0);

    // K loop: slot of tile kt = (kt+1)%3; steady kt=0..27; tails 28..31 peeled
#pragma unroll 1
    for (int it = 0; it < 4; ++it) {
        const int base = it * 6;               // base%6==0 -> slots constexpr per unrolled j
        tile_f<1, true, true, true, 5>(base + 0, ldsp, aRd, bRd, aWr, vsrc, BsrcT, sdstB, vs, acc);
        tile_f<2, true, true, true, 5>(base + 1, ldsp, aRd, bRd, aWr, vsrc, BsrcT, sdstB, vs, acc);
        tile_f<0, true, true, true, 5>(base + 2, ldsp, aRd, bRd, aWr, vsrc, BsrcT, sdstB, vs, acc);
        tile_f<1, true, true, true, 5>(base + 3, ldsp, aRd, bRd, aWr, vsrc, BsrcT, sdstB, vs, acc);
        tile_f<2, true, true, true, 5>(base + 4, ldsp, aRd, bRd, aWr, vsrc, BsrcT, sdstB, vs, acc);
        tile_f<0, true, true, true, 5>(base + 5, ldsp, aRd, bRd, aWr, vsrc, BsrcT, sdstB, vs, acc);
    }
    tile_f<1, true, true, true, 5>(24, ldsp, aRd, bRd, aWr, vsrc, BsrcT, sdstB, vs, acc);
    tile_f<2, true, true, true, 5>(25, ldsp, aRd, bRd, aWr, vsrc, BsrcT, sdstB, vs, acc);
    tile_f<0, true, true, true, 5>(26, ldsp, aRd, bRd, aWr, vsrc, BsrcT, sdstB, vs, acc);
    tile_f<1, true, true, true, 5>(27, ldsp, aRd, bRd, aWr, vsrc, BsrcT, sdstB, vs, acc);
    tile_f<2, true, false, true, 4>(28, ldsp, aRd, bRd, aWr, vsrc, BsrcT, sdstB, vs, acc);
    tile_f<0, true, false, true, 4>(29, ldsp, aRd, bRd, aWr, vsrc, BsrcT, sdstB, vs, acc);
    tile_f<1, true, false, false, 0>(30, ldsp, aRd, bRd, aWr, vsrc, BsrcT, sdstB, vs, acc);
    tile_f<2, false, false, false, -1>(31, ldsp, aRd, bRd, aWr, vsrc, BsrcT, sdstB, vs, acc);

    // ---------------- epilogue: out = x + bias + acc ----------------
    // acc C/D mapping (m89/m91): col = lane&15, row = (lane>>4)*4 + j.
    // Bounce (0..34816) overlaps only buf0, whose last reader (tile 30) passed
    // boundary(30); tile 31 reads buf1 only -> no barrier: waves stagger bursts.
    // x prefetched into regs BEFORE the LDS scatter -> 4 loads in flight (MLP).
    const int q  = lane >> 4;
    const int cl = lane & 15;
    const int row0 = mtile * 64;
    const int col0 = ntile * 512 + w * 64;     // within group
    char* eb = ldsp + (uint32_t)w * 4352u;
    const float4 bias4 = *(const float4*)&bias[g * BLK + col0 + cl * 4];

#pragma unroll
    for (int m = 0; m < 4; ++m) {
        float4 xv[4];
#pragma unroll
        for (int i = 0; i < 4; ++i) {
            const int r = row0 + m * 16 + q + 4 * i;
            xv[i] = *(const float4*)&x[(size_t)r * TOTAL + (size_t)gout * BLK + col0 + cl * 4];
        }
#pragma unroll
        for (int n = 0; n < 4; ++n)
#pragma unroll
            for (int j = 0; j < 4; ++j)
                *(float*)(eb + (q * 4 + j) * 272 + (n * 16 + cl) * 4) = acc[m][n][j];
        asm volatile("s_waitcnt lgkmcnt(0)" ::: "memory");
        __builtin_amdgcn_sched_barrier(0);
#pragma unroll
        for (int i = 0; i < 4; ++i) {
            f32x4 vv = *(const f32x4*)(eb + (q + 4 * i) * 272 + cl * 16);
            const int r = row0 + m * 16 + q + 4 * i;
            const size_t idx = (size_t)r * TOTAL + (size_t)gout * BLK + col0 + cl * 4;
            float4 o;
            o.x = xv[i].x + bias4.x + vv[0];
            o.y = xv[i].y + bias4.y + vv[1];
            o.z = xv[i].z + bias4.z + vv[2];
            o.w = xv[i].w + bias4.w + vv[3];
            *(float4*)&out[idx] = o;
        }
        asm volatile("s_waitcnt lgkmcnt(0)" ::: "memory");
        __builtin_amdgcn_sched_barrier(0);
    }
}

// ---------- fallback (ws too small): correct but slow ----------

__global__ void k_naive(const float* __restrict__ x, const float* __restrict__ v,
                        const float* __restrict__ W, const float* __restrict__ b,
                        float* __restrict__ out) {
    __shared__ float hv[BLK];
    const int bid = blockIdx.x;
    const int quarter = bid & 3;
    const int g = (bid >> 2) & 7;
    const int row = bid >> 5;
    for (int i = threadIdx.x; i < BLK; i += 256)
        hv[i] = tanhf(v[(size_t)row * TOTAL + g * BLK + i]);
    __syncthreads();
    const int o = quarter * 256 + threadIdx.x;
    const float* wrow = W + ((size_t)g * BLK + o) * BLK;
    float s = 0.f;
    for (int i = 0; i < BLK; ++i) s += hv[i] * wrow[i];
    const size_t oi = (size_t)row * TOTAL + (size_t)((g + 1) & 7) * BLK + o;
    out[oi] = x[oi] + b[g * BLK + o] + s;
}

// ---------- launch ----------

extern "C" void kernel_launch(void* const* d_in, const int* in_sizes, int n_in,
                              void* d_out, int out_size, void* d_ws, size_t ws_size,
                              hipStream_t stream) {
    const float* x = (const float*)d_in[0];
    const float* v = (const float*)d_in[1];
    const float* W = (const float*)d_in[2];
    const float* b = (const float*)d_in[3];
    float* out = (float*)d_out;

    const size_t needW = (size_t)KGRP * BLK * BLK * sizeof(unsigned short);   // 16 MB

    if (ws_size >= needW) {
        unsigned short* Wb = (unsigned short*)d_ws;
        k_wcast<<<1024, 256, 0, stream>>>((const float4*)W, (ushort4*)Wb);
        k_main<<<1024, 512, 0, stream>>>(v, Wb, x, b, out);
    } else {
        k_naive<<<BATCH * KGRP * 4, 256, 0, stream>>>(x, v, W, b, out);
    }
}